// Round 8
// baseline (769.308 us; speedup 1.0000x reference)
//
#include <hip/hip_runtime.h>
#include <hip/hip_bf16.h>
#include <stdint.h>

#define T_SEQ 336
#define NKT   11        // K-tiles of 32 (336 -> 352; pad nullified by apack zeros)
#define P_LEN 720
#define NM16  48        // 16-row p-blocks in apack (768 rows, zero-padded)
#define C_LEN 1782
#define NB    64
#define MS    128       // rows per m-slice (8 m16-blocks)
#define NMS   6
#define CHW   896       // cols per c-half
#define NGRP  28        // 32-col groups per half

typedef __attribute__((ext_vector_type(4))) float f32x4;
typedef __attribute__((ext_vector_type(8))) short s16x8;

__device__ __forceinline__ unsigned short f2bf(float f) {
  unsigned int u = __builtin_bit_cast(unsigned int, f);
  u += 0x7FFFu + ((u >> 16) & 1u);   // RNE
  return (unsigned short)(u >> 16);
}

// Weff[p,k] = Ws[p,k] + 0.2*sum_{t in win(k)} (Wt-Ws)[p,t], packed in MFMA
// A-fragment order: block m16*NKT+kt holds 64 lanes x 16B; lane lg*16+l16
// carries W[m16*16+l16][kt*32+lg*8+j], j=0..7. Zero-padded p>=720, k>=336.
__global__ __launch_bounds__(64) void prep_w(
    const float* __restrict__ Ws, const float* __restrict__ bs,
    const float* __restrict__ Wt, const float* __restrict__ bt,
    unsigned short* __restrict__ apack, float* __restrict__ bias) {
  const int p   = blockIdx.x;          // 0..767
  const int tid = threadIdx.x;         // 0..63
  if (tid < NKT * 4) {
    const int kt = tid >> 2;
    const int lg = tid & 3;
    const float* wsr = Ws + (size_t)p * T_SEQ;
    const float* wtr = Wt + (size_t)p * T_SEQ;
    union { s16x8 v; unsigned short u[8]; } pk;
#pragma unroll
    for (int j = 0; j < 8; ++j) {
      const int k = kt * 32 + lg * 8 + j;
      float val = 0.f;
      if (p < P_LEN && k < T_SEQ) {
        float d;
        if (k == 0) {
          d = 3.f*(wtr[0]-wsr[0]) + 2.f*(wtr[1]-wsr[1]) + (wtr[2]-wsr[2]);
        } else if (k == T_SEQ-1) {
          d = 3.f*(wtr[T_SEQ-1]-wsr[T_SEQ-1]) + 2.f*(wtr[T_SEQ-2]-wsr[T_SEQ-2])
              + (wtr[T_SEQ-3]-wsr[T_SEQ-3]);
        } else {
          int lo = (k-2 < 0) ? 0 : k-2;
          int hi = (k+2 > T_SEQ-1) ? T_SEQ-1 : k+2;
          d = 0.f;
          for (int t = lo; t <= hi; ++t) d += wtr[t]-wsr[t];
        }
        val = wsr[k] + 0.2f*d;
      }
      pk.u[j] = f2bf(val);
    }
    const int m16 = p >> 4;
    const int l16 = p & 15;
    *(s16x8*)&apack[(size_t)(((m16*NKT + kt) * 64) + lg*16 + l16) * 8] = pk.v;
  }
  if (tid == 0 && p < P_LEN) bias[p] = bs[p] + bt[p];
}

// O[b,p,c] = relu( sum_k Weff[p,k] * X[b,k,c] + bias[p] )
// A-stationary: the 128-row A-slice (88KB, fragment-packed) is loaded to LDS
// ONCE (one barrier total). 8 waves; each wave sweeps 32-col output groups:
// per kt: 16 direct-x dword loads (depth-2, 3 static slots) + 8 conflict-free
// ds_read_b128 A-frags + 16 MFMA. No K-staging, no per-step barrier.
__global__ __launch_bounds__(512) void gemm_kernel(
    const float* __restrict__ x, const unsigned short* __restrict__ apack,
    const float* __restrict__ bias, float* __restrict__ out) {
  __shared__ __align__(16) unsigned short aLDS[8 * NKT * 512];  // 88 KiB

  // 768 blocks = 8 XCD * 96; consecutive-on-XCD = same (b,chalf), m varies
  const int bid = blockIdx.x;
  const int swz = (bid & 7) * 96 + (bid >> 3);
  const int ms  = swz % NMS;
  const int r_  = swz / NMS;
  const int ch  = r_ & 1;
  const int b   = r_ >> 1;

  const int tid  = threadIdx.x;
  const int lane = tid & 63;
  const int wid  = tid >> 6;     // 0..7
  const int l16  = lane & 15;
  const int lg   = lane >> 4;

  const float* xb = x + (size_t)b * T_SEQ * C_LEN;

  // ---- stage A-slice (88KB contiguous) via global_load_lds, once ----
  {
    const char* asrc = (const char*)(apack + (size_t)ms * 8 * NKT * 512);
#pragma unroll
    for (int i = 0; i < 11; ++i) {
      const char* src = asrc + i * 8192 + wid * 1024 + lane * 16;
      char* dst = (char*)aLDS + i * 8192 + wid * 1024;   // wave-uniform base
      __builtin_amdgcn_global_load_lds(
          (const __attribute__((address_space(1))) unsigned int*)src,
          (__attribute__((address_space(3))) unsigned int*)dst, 16, 0, 0);
    }
  }

  // bias for this wave's 32 row-slots (hoisted; fixed per thread)
  float bv[8][4];
#pragma unroll
  for (int m = 0; m < 8; ++m) {
    const int pb0 = ms * MS + m * 16 + lg * 4;
#pragma unroll
    for (int r = 0; r < 4; ++r)
      bv[m][r] = (pb0 + r < P_LEN) ? bias[pb0 + r] : 0.f;
  }

  __syncthreads();   // the only barrier

  const size_t ob = (size_t)b * P_LEN * C_LEN;

#define LOADB(F, KT)                                                           \
  {                                                                            \
    _Pragma("unroll")                                                          \
    for (int j = 0; j < 8; ++j) {                                              \
      int k_ = (KT) * 32 + lg * 8 + j;                                         \
      if ((KT) == NKT - 1 && k_ > T_SEQ - 1) k_ = T_SEQ - 1;                   \
      const float* rp_ = xb + (size_t)k_ * C_LEN;                              \
      F[j]     = rp_[cA];                                                      \
      F[8 + j] = rp_[cB];                                                      \
    }                                                                          \
  }

#define KTBODY(KT, FC, FP)                                                     \
  {                                                                            \
    if ((KT) + 2 < NKT) LOADB(FP, (KT) + 2);                                   \
    s16x8 bfv_[2];                                                             \
    _Pragma("unroll")                                                          \
    for (int n = 0; n < 2; ++n) {                                              \
      union { s16x8 v; uint32_t dw[4]; } bu_;                                  \
      _Pragma("unroll")                                                        \
      for (int h = 0; h < 4; ++h) {                                            \
        uint32_t rr_;                                                          \
        asm("v_cvt_pk_bf16_f32 %0, %1, %2"                                     \
            : "=v"(rr_) : "v"(FC[n*8 + 2*h]), "v"(FC[n*8 + 2*h + 1]));         \
        bu_.dw[h] = rr_;                                                       \
      }                                                                        \
      bfv_[n] = bu_.v;                                                         \
    }                                                                          \
    _Pragma("unroll")                                                          \
    for (int m = 0; m < 8; ++m) {                                              \
      const s16x8 af_ = *(const s16x8*)&aLDS[(m * NKT + (KT)) * 512 + lane*8]; \
      acc[m][0] = __builtin_amdgcn_mfma_f32_16x16x32_bf16(                     \
          af_, bfv_[0], acc[m][0], 0, 0, 0);                                   \
      acc[m][1] = __builtin_amdgcn_mfma_f32_16x16x32_bf16(                     \
          af_, bfv_[1], acc[m][1], 0, 0, 0);                                   \
    }                                                                          \
  }

  for (int g = wid; g < NGRP; g += 8) {
    const int cg0 = ch * CHW + g * 32;
    int cA = cg0 + l16;      if (cA > C_LEN - 1) cA = C_LEN - 1;
    int cB = cg0 + 16 + l16; if (cB > C_LEN - 1) cB = C_LEN - 1;

    f32x4 acc[8][2] = {};
    float f0[16], f1[16], f2[16];

    LOADB(f0, 0);
    LOADB(f1, 1);
    KTBODY(0, f0, f2)
    KTBODY(1, f1, f0)
    KTBODY(2, f2, f1)
    KTBODY(3, f0, f2)
    KTBODY(4, f1, f0)
    KTBODY(5, f2, f1)
    KTBODY(6, f0, f2)
    KTBODY(7, f1, f0)
    KTBODY(8, f2, f1)
    KTBODY(9, f0, f2)
    KTBODY(10, f1, f0)

    // epilogue: bias + relu + masked store. C/D: row = lg*4 + r, col = l16
#pragma unroll
    for (int m = 0; m < 8; ++m) {
      const int pb0 = ms * MS + m * 16 + lg * 4;
      if (pb0 < P_LEN) {                    // 720%4==0 -> uniform per fragment
#pragma unroll
        for (int n = 0; n < 2; ++n) {
          const int cc = cg0 + n * 16 + l16;
          if (cc < C_LEN) {
#pragma unroll
            for (int r = 0; r < 4; ++r) {
              float vv = acc[m][n][r] + bv[m][r];
              out[ob + (size_t)(pb0 + r) * C_LEN + cc] = fmaxf(vv, 0.f);
            }
          }
        }
      }
    }
  }
#undef KTBODY
#undef LOADB
}

extern "C" void kernel_launch(void* const* d_in, const int* in_sizes, int n_in,
                              void* d_out, int out_size, void* d_ws, size_t ws_size,
                              hipStream_t stream) {
  (void)in_sizes; (void)n_in; (void)out_size; (void)ws_size;
  const float* x  = (const float*)d_in[0];
  const float* Ws = (const float*)d_in[1];
  const float* bs = (const float*)d_in[2];
  const float* Wt = (const float*)d_in[3];
  const float* bt = (const float*)d_in[4];
  float* out = (float*)d_out;

  // ws: Apack (48*11 blocks * 1KB = 540672 B) then bias (720 f32)
  unsigned short* apack = (unsigned short*)d_ws;
  float* biasp = (float*)((char*)d_ws + (size_t)NM16 * NKT * 1024);

  prep_w<<<dim3(768), dim3(64), 0, stream>>>(Ws, bs, Wt, bt, apack, biasp);
  gemm_kernel<<<dim3(NB * 2 * NMS), dim3(512), 0, stream>>>(x, apack, biasp, out);
}

// Round 9
// 205.549 us; speedup vs baseline: 3.7427x; 3.7427x over previous
//
#include <hip/hip_runtime.h>
#include <hip/hip_bf16.h>
#include <stdint.h>

#define T_SEQ 336
#define NKT   11        // K-tiles of 32 (336 -> 352; tail zeroed in LDS, apack zero-padded)
#define P_LEN 720
#define NM16  48        // 16-row p-blocks in apack (768 rows, zero-padded)
#define C_LEN 1782
#define NB    64
#define CTILE 224       // cols per block (8 tiles -> 1792, clamped/masked)
#define BPITCH 360      // LDS row pitch (bf16): 720B -> lane stride 180 dw = 2-way free

typedef __attribute__((ext_vector_type(4))) float f32x4;
typedef __attribute__((ext_vector_type(8))) short s16x8;

__device__ __forceinline__ unsigned short f2bf(float f) {
  unsigned int u = __builtin_bit_cast(unsigned int, f);
  u += 0x7FFFu + ((u >> 16) & 1u);   // RNE
  return (unsigned short)(u >> 16);
}

// Weff[p,k] = Ws[p,k] + 0.2*sum_{t in win(k)} (Wt-Ws)[p,t], packed in MFMA
// A-fragment order: block m16*NKT+kt holds 64 lanes x 16B; lane lg*16+l16
// carries W[m16*16+l16][kt*32+lg*8+j], j=0..7. Zero-padded p>=720, k>=336.
__global__ __launch_bounds__(64) void prep_w(
    const float* __restrict__ Ws, const float* __restrict__ bs,
    const float* __restrict__ Wt, const float* __restrict__ bt,
    unsigned short* __restrict__ apack, float* __restrict__ bias) {
  const int p   = blockIdx.x;          // 0..767
  const int tid = threadIdx.x;         // 0..63
  if (tid < NKT * 4) {
    const int kt = tid >> 2;
    const int lg = tid & 3;
    const float* wsr = Ws + (size_t)p * T_SEQ;
    const float* wtr = Wt + (size_t)p * T_SEQ;
    union { s16x8 v; unsigned short u[8]; } pk;
#pragma unroll
    for (int j = 0; j < 8; ++j) {
      const int k = kt * 32 + lg * 8 + j;
      float val = 0.f;
      if (p < P_LEN && k < T_SEQ) {
        float d;
        if (k == 0) {
          d = 3.f*(wtr[0]-wsr[0]) + 2.f*(wtr[1]-wsr[1]) + (wtr[2]-wsr[2]);
        } else if (k == T_SEQ-1) {
          d = 3.f*(wtr[T_SEQ-1]-wsr[T_SEQ-1]) + 2.f*(wtr[T_SEQ-2]-wsr[T_SEQ-2])
              + (wtr[T_SEQ-3]-wsr[T_SEQ-3]);
        } else {
          int lo = (k-2 < 0) ? 0 : k-2;
          int hi = (k+2 > T_SEQ-1) ? T_SEQ-1 : k+2;
          d = 0.f;
          for (int t = lo; t <= hi; ++t) d += wtr[t]-wsr[t];
        }
        val = wsr[k] + 0.2f*d;
      }
      pk.u[j] = f2bf(val);
    }
    const int m16 = p >> 4;
    const int l16 = p & 15;
    *(s16x8*)&apack[(size_t)(((m16*NKT + kt) * 64) + lg*16 + l16) * 8] = pk.v;
  }
  if (tid == 0 && p < P_LEN) bias[p] = bs[p] + bt[p];
}

// O[b,p,c] = relu( sum_k Weff[p,k] * X[b,k,c] + bias[p] )
// Block = (batch, 224-col slice) x ALL 768 p-rows. x panel staged to LDS ONCE
// (x crosses the memory hierarchy exactly once chip-wide); one barrier; then
// sweep 3 m-pairs x 4 col-groups x 11 kt with A from L2-hot packed Weff
// (528 KB, read by every block -> L2-resident) and B from LDS (2-way free).
__global__ __launch_bounds__(512, 2) void gemm_kernel(
    const float* __restrict__ x, const unsigned short* __restrict__ apack,
    const float* __restrict__ bias, float* __restrict__ out) {
  __shared__ __align__(16) unsigned short Bp[CTILE * BPITCH];   // 161280 B

  const int bid = blockIdx.x;
  const int ct  = bid & 7;        // XCD k sweeps col-stripe k (round-robin map)
  const int b   = bid >> 3;
  const int c0  = ct * CTILE;

  const int tid  = threadIdx.x;
  const int lane = tid & 63;
  const int wid  = tid >> 6;      // 0..7
  const int l16  = lane & 15;
  const int lg   = lane >> 4;

  const float* xb = x + (size_t)b * T_SEQ * C_LEN;
  const s16x8* ap = (const s16x8*)apack;

  // ---- stage x panel: fp32 -> bf16, transposed to [c][k], pitch 360 ----
  // unit i = (kg, cp): cols c0+2cp..+1, rows kg*8..kg*8+7  (42*8 = 336 exact)
  for (int i = tid; i < 112 * 42; i += 512) {
    const int cp = i % 112;
    const int kg = i / 112;
    const int c  = c0 + cp * 2;
    const int cA = (c     < C_LEN) ? c     : C_LEN - 1;
    const int cB = (c + 1 < C_LEN) ? c + 1 : C_LEN - 1;   // junk cols masked at store
    float fa[8], fb[8];
#pragma unroll
    for (int j = 0; j < 8; ++j) {
      const float* rp = xb + (size_t)(kg * 8 + j) * C_LEN;
      fa[j] = rp[cA];
      fb[j] = rp[cB];
    }
    union { s16x8 v; uint32_t dw[4]; } pa, pb;
#pragma unroll
    for (int h = 0; h < 4; ++h) {
      uint32_t ra, rb;
      asm("v_cvt_pk_bf16_f32 %0, %1, %2" : "=v"(ra) : "v"(fa[2*h]), "v"(fa[2*h+1]));
      asm("v_cvt_pk_bf16_f32 %0, %1, %2" : "=v"(rb) : "v"(fb[2*h]), "v"(fb[2*h+1]));
      pa.dw[h] = ra; pb.dw[h] = rb;
    }
    *(s16x8*)&Bp[(cp * 2)     * BPITCH + kg * 8] = pa.v;
    *(s16x8*)&Bp[(cp * 2 + 1) * BPITCH + kg * 8] = pb.v;
  }
  // zero k-tail 336..359 (kt=10 reads k up to 351)
  {
    const s16x8 z = {};
    for (int i = tid; i < CTILE * 3; i += 512)
      *(s16x8*)&Bp[(i / 3) * BPITCH + T_SEQ + (i % 3) * 8] = z;
  }
  __syncthreads();   // the only barrier

  const size_t ob = (size_t)b * P_LEN * C_LEN;

  // subtile: 32 p-rows (m16a, m16a+1) x NFR 16-col fragments at c-offset CGO
#define SUBTILE(CGO, NFR)                                                      \
  {                                                                            \
    f32x4 acc[2][NFR] = {};                                                    \
    _Pragma("unroll")                                                          \
    for (int kt = 0; kt < NKT; ++kt) {                                         \
      const s16x8 af0 = ap[(size_t)((m16a)     * NKT + kt) * 64 + lane];       \
      const s16x8 af1 = ap[(size_t)((m16a + 1) * NKT + kt) * 64 + lane];       \
      s16x8 bf[NFR];                                                           \
      _Pragma("unroll")                                                        \
      for (int n = 0; n < NFR; ++n)                                            \
        bf[n] = *(const s16x8*)&Bp[((CGO) + n * 16 + l16) * BPITCH             \
                                   + kt * 32 + lg * 8];                        \
      _Pragma("unroll")                                                        \
      for (int n = 0; n < NFR; ++n) {                                          \
        acc[0][n] = __builtin_amdgcn_mfma_f32_16x16x32_bf16(                   \
            af0, bf[n], acc[0][n], 0, 0, 0);                                   \
        acc[1][n] = __builtin_amdgcn_mfma_f32_16x16x32_bf16(                   \
            af1, bf[n], acc[1][n], 0, 0, 0);                                   \
      }                                                                        \
    }                                                                          \
    _Pragma("unroll")                                                          \
    for (int m = 0; m < 2; ++m) {                                              \
      const int m16 = m16a + m;                                                \
      if (m16 < 45) {               /* p < 720, uniform per fragment */        \
        const int pb0 = m16 * 16 + lg * 4;                                     \
        _Pragma("unroll")                                                      \
        for (int n = 0; n < NFR; ++n) {                                        \
          const int cc = c0 + (CGO) + n * 16 + l16;                            \
          if (cc < C_LEN) {                                                    \
            _Pragma("unroll")                                                  \
            for (int r = 0; r < 4; ++r) {                                      \
              float vv = acc[m][n][r] + bv[m][r];                              \
              out[ob + (size_t)(pb0 + r) * C_LEN + cc] = fmaxf(vv, 0.f);       \
            }                                                                  \
          }                                                                    \
        }                                                                      \
      }                                                                        \
    }                                                                          \
  }

#pragma unroll 1
  for (int mp = 0; mp < 3; ++mp) {
    const int m16a = mp * 16 + wid * 2;     // covers 0..47 over (mp, wid, m)
    float bv[2][4];
#pragma unroll
    for (int m = 0; m < 2; ++m) {
      const int pb0 = (m16a + m) * 16 + lg * 4;
#pragma unroll
      for (int r = 0; r < 4; ++r)
        bv[m][r] = (pb0 + r < P_LEN) ? bias[pb0 + r] : 0.f;
    }
    SUBTILE(0,   4)
    SUBTILE(64,  4)
    SUBTILE(128, 4)
    SUBTILE(192, 2)
  }
#undef SUBTILE
}

extern "C" void kernel_launch(void* const* d_in, const int* in_sizes, int n_in,
                              void* d_out, int out_size, void* d_ws, size_t ws_size,
                              hipStream_t stream) {
  (void)in_sizes; (void)n_in; (void)out_size; (void)ws_size;
  const float* x  = (const float*)d_in[0];
  const float* Ws = (const float*)d_in[1];
  const float* bs = (const float*)d_in[2];
  const float* Wt = (const float*)d_in[3];
  const float* bt = (const float*)d_in[4];
  float* out = (float*)d_out;

  // ws: Apack (48*11 blocks * 1KB = 540672 B) then bias (720 f32)
  unsigned short* apack = (unsigned short*)d_ws;
  float* biasp = (float*)((char*)d_ws + (size_t)NM16 * NKT * 1024);

  prep_w<<<dim3(768), dim3(64), 0, stream>>>(Ws, bs, Wt, bt, apack, biasp);
  gemm_kernel<<<dim3(NB * 8), dim3(512), 0, stream>>>(x, apack, biasp, out);
}

// Round 10
// 198.507 us; speedup vs baseline: 3.8755x; 1.0355x over previous
//
#include <hip/hip_runtime.h>
#include <hip/hip_bf16.h>
#include <stdint.h>

#define T_SEQ 336
#define NKT   11        // K-tiles of 32 (336 -> 352; tail zeroed in LDS, apack zero-padded)
#define P_LEN 720
#define NM16  48        // 16-row p-blocks in apack (768 rows, zero-padded)
#define C_LEN 1782
#define NB    64
#define CTILE 112       // cols per block (16 tiles -> 1792, clamped/masked)
#define NCT   16
#define BPITCH 360      // LDS row pitch (bf16); 80640 B total -> 2 blocks/CU

typedef __attribute__((ext_vector_type(4))) float f32x4;
typedef __attribute__((ext_vector_type(8))) short s16x8;

__device__ __forceinline__ unsigned short f2bf(float f) {
  unsigned int u = __builtin_bit_cast(unsigned int, f);
  u += 0x7FFFu + ((u >> 16) & 1u);   // RNE
  return (unsigned short)(u >> 16);
}

// Weff[p,k] = Ws[p,k] + 0.2*sum_{t in win(k)} (Wt-Ws)[p,t], packed in MFMA
// A-fragment order: block m16*NKT+kt holds 64 lanes x 16B; lane lg*16+l16
// carries W[m16*16+l16][kt*32+lg*8+j], j=0..7. Zero-padded p>=720, k>=336.
__global__ __launch_bounds__(64) void prep_w(
    const float* __restrict__ Ws, const float* __restrict__ bs,
    const float* __restrict__ Wt, const float* __restrict__ bt,
    unsigned short* __restrict__ apack, float* __restrict__ bias) {
  const int p   = blockIdx.x;          // 0..767
  const int tid = threadIdx.x;         // 0..63
  if (tid < NKT * 4) {
    const int kt = tid >> 2;
    const int lg = tid & 3;
    const float* wsr = Ws + (size_t)p * T_SEQ;
    const float* wtr = Wt + (size_t)p * T_SEQ;
    union { s16x8 v; unsigned short u[8]; } pk;
#pragma unroll
    for (int j = 0; j < 8; ++j) {
      const int k = kt * 32 + lg * 8 + j;
      float val = 0.f;
      if (p < P_LEN && k < T_SEQ) {
        float d;
        if (k == 0) {
          d = 3.f*(wtr[0]-wsr[0]) + 2.f*(wtr[1]-wsr[1]) + (wtr[2]-wsr[2]);
        } else if (k == T_SEQ-1) {
          d = 3.f*(wtr[T_SEQ-1]-wsr[T_SEQ-1]) + 2.f*(wtr[T_SEQ-2]-wsr[T_SEQ-2])
              + (wtr[T_SEQ-3]-wsr[T_SEQ-3]);
        } else {
          int lo = (k-2 < 0) ? 0 : k-2;
          int hi = (k+2 > T_SEQ-1) ? T_SEQ-1 : k+2;
          d = 0.f;
          for (int t = lo; t <= hi; ++t) d += wtr[t]-wsr[t];
        }
        val = wsr[k] + 0.2f*d;
      }
      pk.u[j] = f2bf(val);
    }
    const int m16 = p >> 4;
    const int l16 = p & 15;
    *(s16x8*)&apack[(size_t)(((m16*NKT + kt) * 64) + lg*16 + l16) * 8] = pk.v;
  }
  if (tid == 0 && p < P_LEN) bias[p] = bs[p] + bt[p];
}

// O[b,p,c] = relu( sum_k Weff[p,k] * X[b,k,c] + bias[p] )
// Block = (batch, 112-col slice) x ALL 768 p-rows. x panel staged to LDS once
// (float2 loads; x crosses the hierarchy once chip-wide); one barrier; then
// 3 m-pairs x 7 col-frags x 11 kt with A from L2-hot packed Weff (loaded once
// per kt) and B from LDS. 80640 B LDS -> 2 resident blocks/CU: staging of
// block n+1 overlaps compute of block n; 16 waves/CU.
__global__ __launch_bounds__(512, 4) void gemm_kernel(
    const float* __restrict__ x, const unsigned short* __restrict__ apack,
    const float* __restrict__ bias, float* __restrict__ out) {
  __shared__ __align__(16) unsigned short Bp[CTILE * BPITCH];   // 80640 B

  const int bid = blockIdx.x;
  const int ct  = bid & 15;       // consecutive bids -> different XCDs
  const int b   = bid >> 4;
  const int c0  = ct * CTILE;

  const int tid  = threadIdx.x;
  const int lane = tid & 63;
  const int wid  = tid >> 6;      // 0..7
  const int l16  = lane & 15;
  const int lg   = lane >> 4;

  const float* xb = x + (size_t)b * T_SEQ * C_LEN;
  const s16x8* ap = (const s16x8*)apack;

  // ---- stage x panel: fp32 -> bf16, transposed to [c][k], pitch 360 ----
  // unit i = (kg, cp): cols c0+2cp..+1, rows kg*8..kg*8+7 (42*8 = 336 exact)
  for (int i = tid; i < 42 * 56; i += 512) {
    const int cp = i % 56;
    const int kg = i / 56;
    int c = c0 + cp * 2; if (c > C_LEN - 2) c = C_LEN - 2;  // junk masked at store
    float2 v[8];
#pragma unroll
    for (int j = 0; j < 8; ++j)
      v[j] = *(const float2*)(xb + (size_t)(kg * 8 + j) * C_LEN + c);
    union { s16x8 vv; uint32_t dw[4]; } pa, pb;
#pragma unroll
    for (int h = 0; h < 4; ++h) {
      uint32_t ra, rb;
      asm("v_cvt_pk_bf16_f32 %0, %1, %2" : "=v"(ra) : "v"(v[2*h].x), "v"(v[2*h+1].x));
      asm("v_cvt_pk_bf16_f32 %0, %1, %2" : "=v"(rb) : "v"(v[2*h].y), "v"(v[2*h+1].y));
      pa.dw[h] = ra; pb.dw[h] = rb;
    }
    *(s16x8*)&Bp[(cp * 2)     * BPITCH + kg * 8] = pa.vv;
    *(s16x8*)&Bp[(cp * 2 + 1) * BPITCH + kg * 8] = pb.vv;
  }
  // zero k-tail 336..359 (kt=10 reads k up to 351)
  {
    const s16x8 z = {};
    for (int i = tid; i < CTILE * 3; i += 512)
      *(s16x8*)&Bp[(i / 3) * BPITCH + T_SEQ + (i % 3) * 8] = z;
  }
  __syncthreads();   // the only barrier

  const size_t ob = (size_t)b * P_LEN * C_LEN;

#pragma unroll 1
  for (int mp = 0; mp < 3; ++mp) {
    const int m16a = mp * 16 + wid * 2;     // covers 0..47 over (mp, wid, m)
    float bv[2][4];
#pragma unroll
    for (int m = 0; m < 2; ++m) {
      const int pb0 = (m16a + m) * 16 + lg * 4;
#pragma unroll
      for (int r = 0; r < 4; ++r)
        bv[m][r] = (pb0 + r < P_LEN) ? bias[pb0 + r] : 0.f;
    }

    f32x4 acc[2][7] = {};
#pragma unroll
    for (int kt = 0; kt < NKT; ++kt) {
      const s16x8 af0 = ap[(size_t)((m16a)     * NKT + kt) * 64 + lane];
      const s16x8 af1 = ap[(size_t)((m16a + 1) * NKT + kt) * 64 + lane];
      s16x8 bf[7];
#pragma unroll
      for (int n = 0; n < 7; ++n)
        bf[n] = *(const s16x8*)&Bp[(n * 16 + l16) * BPITCH + kt * 32 + lg * 8];
#pragma unroll
      for (int n = 0; n < 7; ++n) {
        acc[0][n] = __builtin_amdgcn_mfma_f32_16x16x32_bf16(
            af0, bf[n], acc[0][n], 0, 0, 0);
        acc[1][n] = __builtin_amdgcn_mfma_f32_16x16x32_bf16(
            af1, bf[n], acc[1][n], 0, 0, 0);
      }
    }

    // epilogue: bias + relu + masked store. C/D: row = lg*4 + r, col = l16
#pragma unroll
    for (int m = 0; m < 2; ++m) {
      const int m16 = m16a + m;
      if (m16 < 45) {               // p < 720, uniform per fragment
        const int pb0 = m16 * 16 + lg * 4;
#pragma unroll
        for (int n = 0; n < 7; ++n) {
          const int cc = c0 + n * 16 + l16;
          if (cc < C_LEN) {
#pragma unroll
            for (int r = 0; r < 4; ++r) {
              float vv = acc[m][n][r] + bv[m][r];
              out[ob + (size_t)(pb0 + r) * C_LEN + cc] = fmaxf(vv, 0.f);
            }
          }
        }
      }
    }
  }
}

extern "C" void kernel_launch(void* const* d_in, const int* in_sizes, int n_in,
                              void* d_out, int out_size, void* d_ws, size_t ws_size,
                              hipStream_t stream) {
  (void)in_sizes; (void)n_in; (void)out_size; (void)ws_size;
  const float* x  = (const float*)d_in[0];
  const float* Ws = (const float*)d_in[1];
  const float* bs = (const float*)d_in[2];
  const float* Wt = (const float*)d_in[3];
  const float* bt = (const float*)d_in[4];
  float* out = (float*)d_out;

  // ws: Apack (48*11 blocks * 1KB = 540672 B) then bias (720 f32)
  unsigned short* apack = (unsigned short*)d_ws;
  float* biasp = (float*)((char*)d_ws + (size_t)NM16 * NKT * 1024);

  prep_w<<<dim3(768), dim3(64), 0, stream>>>(Ws, bs, Wt, bt, apack, biasp);
  gemm_kernel<<<dim3(NB * NCT), dim3(512), 0, stream>>>(x, apack, biasp, out);
}